// Round 1
// baseline (914.142 us; speedup 1.0000x reference)
//
#include <hip/hip_runtime.h>
#include <hip/hip_bf16.h>
#include <float.h>

// Problem constants
#define BQ 512     // batch
#define LQ 12      // L
#define DQ 768     // D
#define TQ 20      // tasks
#define NKQ 100    // keys per task
#define NPQ 10     // prompts per task
#define NKEY (TQ*NKQ)   // 2000 keys per l

// argmin kernel tiling
#define BT 64      // b per block
#define KT 64      // keys per sub-tile
#define DT 32      // d chunk
#define KPC 512    // keys per chunk (padded; masked beyond 2000)
#define NCHUNK 4   // 4*512 = 2048 >= 2000

// ---------------- K1: k2[l*2000+g] = sum_d keys^2 ----------------
__global__ __launch_bounds__(256)
void k2_kernel(const float* __restrict__ keys, float* __restrict__ k2) {
    int wave = threadIdx.x >> 6;
    int lane = threadIdx.x & 63;
    int row = blockIdx.x * 4 + wave;          // 0 .. 23999
    const float* kp = keys + (size_t)row * DQ;
    float s = 0.f;
#pragma unroll
    for (int c = 0; c < 3; ++c) {
        float4 v = *reinterpret_cast<const float4*>(kp + c * 256 + lane * 4);
        s = fmaf(v.x, v.x, s); s = fmaf(v.y, v.y, s);
        s = fmaf(v.z, v.z, s); s = fmaf(v.w, v.w, s);
    }
#pragma unroll
    for (int m = 32; m; m >>= 1) s += __shfl_xor(s, m, 64);
    if (lane == 0) k2[row] = s;
}

// ---------------- K2: per-(l, b-tile, key-chunk) partial argmin ----------------
__global__ __launch_bounds__(256)
void argmin_kernel(const float* __restrict__ xq, const float* __restrict__ keys,
                   const float* __restrict__ k2,
                   float* __restrict__ pval, int* __restrict__ pidx) {
    const int bt    = blockIdx.x;   // 0..7
    const int chunk = blockIdx.y;   // 0..3
    const int l     = blockIdx.z;   // 0..11
    const int tid = threadIdx.x;
    const int tx = tid & 15;        // key dim (16)
    const int ty = tid >> 4;        // b dim (16)
    const int b0 = bt * BT;
    const int g0 = chunk * KPC;

    __shared__ float Xs[BT][DT + 1];  // [b][d], pad -> stride 33 (<=2-way bank alias, free)
    __shared__ float Ks[KT][DT + 1];  // [k][d]

    float rv[4] = {FLT_MAX, FLT_MAX, FLT_MAX, FLT_MAX};
    int   ri[4] = {0x7fffffff, 0x7fffffff, 0x7fffffff, 0x7fffffff};

    const int dq = tid & 7;     // which float4 along d (8 * 4 = 32)
    const int bb = tid >> 3;    // 0..31, row within tile (2 passes)

    for (int kt = 0; kt < KPC / KT; ++kt) {     // 8 sub-tiles of 64 keys
        float acc[4][4] = {{0.f}};
        for (int dc = 0; dc < DQ / DT; ++dc) {  // 24 d-chunks
            const int d0 = dc * DT;
            // stage X tile: 64 b x 32 d (coalesced float4 reads, b32 LDS writes)
#pragma unroll
            for (int p = 0; p < 2; ++p) {
                int b = bb + p * 32;
                float4 v = *reinterpret_cast<const float4*>(
                    &xq[((size_t)(b0 + b) * LQ + l) * DQ + d0 + dq * 4]);
                Xs[b][dq * 4 + 0] = v.x; Xs[b][dq * 4 + 1] = v.y;
                Xs[b][dq * 4 + 2] = v.z; Xs[b][dq * 4 + 3] = v.w;
            }
            // stage K tile: 64 keys x 32 d (masked beyond 2000)
#pragma unroll
            for (int p = 0; p < 2; ++p) {
                int k = bb + p * 32;
                int g = g0 + kt * KT + k;
                float4 v = make_float4(0.f, 0.f, 0.f, 0.f);
                if (g < NKEY)
                    v = *reinterpret_cast<const float4*>(
                        &keys[((size_t)l * NKEY + g) * DQ + d0 + dq * 4]);
                Ks[k][dq * 4 + 0] = v.x; Ks[k][dq * 4 + 1] = v.y;
                Ks[k][dq * 4 + 2] = v.z; Ks[k][dq * 4 + 3] = v.w;
            }
            __syncthreads();
#pragma unroll
            for (int d = 0; d < DT; ++d) {
                float xv[4], kv[4];
#pragma unroll
                for (int i = 0; i < 4; ++i) xv[i] = Xs[ty * 4 + i][d];
#pragma unroll
                for (int j = 0; j < 4; ++j) kv[j] = Ks[tx * 4 + j][d];
#pragma unroll
                for (int i = 0; i < 4; ++i)
#pragma unroll
                    for (int j = 0; j < 4; ++j)
                        acc[i][j] = fmaf(xv[i], kv[j], acc[i][j]);
            }
            __syncthreads();
        }
        // epilogue for this 64-key sub-tile: score = k2 - 2*dot, running min
#pragma unroll
        for (int j = 0; j < 4; ++j) {
            int g = g0 + kt * KT + tx * 4 + j;    // ascending within thread
            if (g < NKEY) {
                float kk = k2[l * NKEY + g];
#pragma unroll
                for (int i = 0; i < 4; ++i) {
                    float s = fmaf(-2.f, acc[i][j], kk);
                    if (s < rv[i]) { rv[i] = s; ri[i] = g; }  // strict < keeps earliest
                }
            }
        }
    }
    // reduce across the 16 key-lanes (tx) within each wave; tie -> smaller idx
#pragma unroll
    for (int m = 1; m < 16; m <<= 1) {
#pragma unroll
        for (int i = 0; i < 4; ++i) {
            float ov = __shfl_xor(rv[i], m, 64);
            int   oi = __shfl_xor(ri[i], m, 64);
            if (ov < rv[i] || (ov == rv[i] && oi < ri[i])) { rv[i] = ov; ri[i] = oi; }
        }
    }
    if (tx == 0) {
#pragma unroll
        for (int i = 0; i < 4; ++i) {
            int b = b0 + ty * 4 + i;
            size_t o = ((size_t)l * BQ + b) * NCHUNK + chunk;
            pval[o] = rv[i];
            pidx[o] = ri[i];
        }
    }
}

// ---------------- K3: combine partials + gather prompts ----------------
__global__ __launch_bounds__(256)
void gather_kernel(const float* __restrict__ prompts,
                   const float* __restrict__ pval, const int* __restrict__ pidx,
                   float* __restrict__ out) {
    const int b = blockIdx.x;   // 0..511
    const int l = blockIdx.y;   // 0..11
    size_t base = ((size_t)l * BQ + b) * NCHUNK;
    float bv = FLT_MAX; int bi = 0x7fffffff;
#pragma unroll
    for (int c = 0; c < NCHUNK; ++c) {
        float v = pval[base + c]; int idx = pidx[base + c];
        if (v < bv || (v == bv && idx < bi)) { bv = v; bi = idx; }
    }
    int task = bi / NKQ;
    const float4* src = reinterpret_cast<const float4*>(
        prompts + ((size_t)l * TQ + task) * (NPQ * DQ));
    float4* dst = reinterpret_cast<float4*>(
        out + ((size_t)l * BQ + b) * (size_t)(NPQ * DQ));
    const int n4 = NPQ * DQ / 4;  // 1920
    for (int i = threadIdx.x; i < n4; i += blockDim.x) dst[i] = src[i];
    if (b == 0 && l == 0 && threadIdx.x == 0)
        out[(size_t)LQ * BQ * NPQ * DQ] = 0.0f;   // trailing scalar output (0.0)
}

extern "C" void kernel_launch(void* const* d_in, const int* in_sizes, int n_in,
                              void* d_out, int out_size, void* d_ws, size_t ws_size,
                              hipStream_t stream) {
    const float* xq      = (const float*)d_in[0];  // (B,L,D)
    const float* keys    = (const float*)d_in[1];  // (L,T,NK,D)
    const float* prompts = (const float*)d_in[2];  // (L,T,NP,D)
    float* out = (float*)d_out;

    // workspace layout (floats): [0,24000) k2 | [32768, +24576) pval | then pidx
    float* k2   = (float*)d_ws;
    float* pval = (float*)d_ws + 32768;
    int*   pidx = (int*)((float*)d_ws + 65536);

    hipLaunchKernelGGL(k2_kernel, dim3((LQ * NKEY) / 4), dim3(256), 0, stream, keys, k2);
    hipLaunchKernelGGL(argmin_kernel, dim3(8, NCHUNK, LQ), dim3(256), 0, stream,
                       xq, keys, k2, pval, pidx);
    hipLaunchKernelGGL(gather_kernel, dim3(BQ, LQ), dim3(256), 0, stream,
                       prompts, pval, pidx, out);
}

// Round 2
// 519.301 us; speedup vs baseline: 1.7603x; 1.7603x over previous
//
#include <hip/hip_runtime.h>
#include <hip/hip_bf16.h>
#include <float.h>

// Problem constants
#define BQ 512     // batch
#define LQ 12      // L
#define DQ 768     // D
#define TQ 20      // tasks
#define NKQ 100    // keys per task
#define NPQ 10     // prompts per task
#define NKEY (TQ*NKQ)   // 2000 keys per l

// argmin kernel tiling
#define BT 128     // b per block
#define KT 128     // keys per block (= chunk)
#define DT 32      // d chunk
#define NCH 16     // ceil(2000/128)
#define GS 12      // LDS group stride: 8 data + 4 pad words (keeps 16B align)
#define RS (16*GS + 4)   // d-row stride in words = 196 (== 4 mod 32)

// idx into transposed group-padded LDS tile: row r (b or k), depth d
__device__ __forceinline__ int lidx(int d, int r) {
    return d * RS + (r >> 3) * GS + (r & 7);
}

// ---------------- K1: k2[l*2000+g] = sum_d keys^2 ----------------
__global__ __launch_bounds__(256)
void k2_kernel(const float* __restrict__ keys, float* __restrict__ k2) {
    int wave = threadIdx.x >> 6;
    int lane = threadIdx.x & 63;
    int row = blockIdx.x * 4 + wave;          // 0 .. 23999
    const float* kp = keys + (size_t)row * DQ;
    float s = 0.f;
#pragma unroll
    for (int c = 0; c < 3; ++c) {
        float4 v = *reinterpret_cast<const float4*>(kp + c * 256 + lane * 4);
        s = fmaf(v.x, v.x, s); s = fmaf(v.y, v.y, s);
        s = fmaf(v.z, v.z, s); s = fmaf(v.w, v.w, s);
    }
#pragma unroll
    for (int m = 32; m; m >>= 1) s += __shfl_xor(s, m, 64);
    if (lane == 0) k2[row] = s;
}

// ---------------- K2: per-(l, b-tile, key-chunk) partial argmin ----------------
// 128b x 128k tile, 8x8 per thread, transposed LDS with ds_read_b128 fragments.
__global__ __launch_bounds__(256)
void argmin_kernel(const float* __restrict__ xq, const float* __restrict__ keys,
                   const float* __restrict__ k2,
                   float* __restrict__ pval, int* __restrict__ pidx) {
    const int bt    = blockIdx.x;   // 0..3
    const int chunk = blockIdx.y;   // 0..15
    const int l     = blockIdx.z;   // 0..11
    const int tid = threadIdx.x;
    const int tx = tid & 15;        // key dim (16 lanes)
    const int ty = tid >> 4;        // b dim (16)
    const int b0 = bt * BT;
    const int g0 = chunk * KT;

    __shared__ float Xs[DT * RS];   // [d][b-groups], 25088 B
    __shared__ float Ks[DT * RS];   // [d][k-groups], 25088 B

    float acc[8][8];
#pragma unroll
    for (int i = 0; i < 8; ++i)
#pragma unroll
        for (int j = 0; j < 8; ++j) acc[i][j] = 0.f;

    const int dq = tid & 7;     // float4 slot along d (8*4 = 32)
    const int r0 = tid >> 3;    // 0..31, row base (4 passes of 32)

    for (int dc = 0; dc < DQ / DT; ++dc) {
        const int d0 = dc * DT;
        // stage X tile: 128 b x 32 d, transposed into Xs[d][b]
#pragma unroll
        for (int p = 0; p < 4; ++p) {
            int r = r0 + p * 32;
            float4 v = *reinterpret_cast<const float4*>(
                &xq[((size_t)(b0 + r) * LQ + l) * DQ + d0 + dq * 4]);
            Xs[lidx(dq * 4 + 0, r)] = v.x;
            Xs[lidx(dq * 4 + 1, r)] = v.y;
            Xs[lidx(dq * 4 + 2, r)] = v.z;
            Xs[lidx(dq * 4 + 3, r)] = v.w;
        }
        // stage K tile: 128 k x 32 d (clamped addr; epilogue guards validity)
#pragma unroll
        for (int p = 0; p < 4; ++p) {
            int r = r0 + p * 32;
            int g = g0 + r; if (g >= NKEY) g = NKEY - 1;
            float4 v = *reinterpret_cast<const float4*>(
                &keys[((size_t)l * NKEY + g) * DQ + d0 + dq * 4]);
            Ks[lidx(dq * 4 + 0, r)] = v.x;
            Ks[lidx(dq * 4 + 1, r)] = v.y;
            Ks[lidx(dq * 4 + 2, r)] = v.z;
            Ks[lidx(dq * 4 + 3, r)] = v.w;
        }
        __syncthreads();
#pragma unroll 8
        for (int d = 0; d < DT; ++d) {
            const float4 xa = *reinterpret_cast<const float4*>(&Xs[d * RS + ty * GS]);
            const float4 xb = *reinterpret_cast<const float4*>(&Xs[d * RS + ty * GS + 4]);
            const float4 ka = *reinterpret_cast<const float4*>(&Ks[d * RS + tx * GS]);
            const float4 kb = *reinterpret_cast<const float4*>(&Ks[d * RS + tx * GS + 4]);
            float xr[8] = {xa.x, xa.y, xa.z, xa.w, xb.x, xb.y, xb.z, xb.w};
            float kr[8] = {ka.x, ka.y, ka.z, ka.w, kb.x, kb.y, kb.z, kb.w};
#pragma unroll
            for (int i = 0; i < 8; ++i)
#pragma unroll
                for (int j = 0; j < 8; ++j)
                    acc[i][j] = fmaf(xr[i], kr[j], acc[i][j]);
        }
        __syncthreads();
    }

    // epilogue: score = k2 - 2*dot; per-thread min over 8 keys (ascending g)
    float bv[8]; int bi[8];
#pragma unroll
    for (int i = 0; i < 8; ++i) { bv[i] = FLT_MAX; bi[i] = 0x7fffffff; }
#pragma unroll
    for (int j = 0; j < 8; ++j) {
        int g = g0 + tx * 8 + j;
        if (g < NKEY) {
            float kk = k2[l * NKEY + g];
#pragma unroll
            for (int i = 0; i < 8; ++i) {
                float s = fmaf(-2.f, acc[i][j], kk);
                if (s < bv[i]) { bv[i] = s; bi[i] = g; }  // strict < keeps earliest
            }
        }
    }
    // reduce across the 16 key-lanes (tx); tie -> smaller idx
#pragma unroll
    for (int m = 1; m < 16; m <<= 1) {
#pragma unroll
        for (int i = 0; i < 8; ++i) {
            float ov = __shfl_xor(bv[i], m, 64);
            int   oi = __shfl_xor(bi[i], m, 64);
            if (ov < bv[i] || (ov == bv[i] && oi < bi[i])) { bv[i] = ov; bi[i] = oi; }
        }
    }
    if (tx == 0) {
#pragma unroll
        for (int i = 0; i < 8; ++i) {
            int b = b0 + ty * 8 + i;
            size_t o = ((size_t)l * BQ + b) * NCH + chunk;
            pval[o] = bv[i];
            pidx[o] = bi[i];
        }
    }
}

// ---------------- K3: combine partials + gather prompts ----------------
__global__ __launch_bounds__(256)
void gather_kernel(const float* __restrict__ prompts,
                   const float* __restrict__ pval, const int* __restrict__ pidx,
                   float* __restrict__ out) {
    const int b = blockIdx.x;   // 0..511
    const int l = blockIdx.y;   // 0..11
    size_t base = ((size_t)l * BQ + b) * NCH;
    float bv = FLT_MAX; int bi = 0x7fffffff;
#pragma unroll
    for (int c = 0; c < NCH; ++c) {
        float v = pval[base + c]; int idx = pidx[base + c];
        if (v < bv || (v == bv && idx < bi)) { bv = v; bi = idx; }
    }
    int task = bi / NKQ;
    const float4* src = reinterpret_cast<const float4*>(
        prompts + ((size_t)l * TQ + task) * (NPQ * DQ));
    float4* dst = reinterpret_cast<float4*>(
        out + ((size_t)l * BQ + b) * (size_t)(NPQ * DQ));
    const int n4 = NPQ * DQ / 4;  // 1920
    for (int i = threadIdx.x; i < n4; i += blockDim.x) dst[i] = src[i];
    if (b == 0 && l == 0 && threadIdx.x == 0)
        out[(size_t)LQ * BQ * NPQ * DQ] = 0.0f;   // trailing scalar output (0.0)
}

extern "C" void kernel_launch(void* const* d_in, const int* in_sizes, int n_in,
                              void* d_out, int out_size, void* d_ws, size_t ws_size,
                              hipStream_t stream) {
    const float* xq      = (const float*)d_in[0];  // (B,L,D)
    const float* keys    = (const float*)d_in[1];  // (L,T,NK,D)
    const float* prompts = (const float*)d_in[2];  // (L,T,NP,D)
    float* out = (float*)d_out;

    // workspace layout (floats): [0,24000) k2 | [24064, +98304) pval | then pidx
    float* k2   = (float*)d_ws;
    float* pval = (float*)d_ws + 24064;
    int*   pidx = (int*)((float*)d_ws + 24064 + 98304);

    hipLaunchKernelGGL(k2_kernel, dim3((LQ * NKEY) / 4), dim3(256), 0, stream, keys, k2);
    hipLaunchKernelGGL(argmin_kernel, dim3(4, NCH, LQ), dim3(256), 0, stream,
                       xq, keys, k2, pval, pidx);
    hipLaunchKernelGGL(gather_kernel, dim3(BQ, LQ), dim3(256), 0, stream,
                       prompts, pval, pidx, out);
}